// Round 1
// baseline (597.188 us; speedup 1.0000x reference)
//
#include <hip/hip_runtime.h>
#include <hip/hip_bf16.h>
#include <cstdint>

// MQA: B=4, S=2048, HIDDEN=1024, HEADS=16, HEAD_DIM=64
#define HIDDEN 1024
#define HEADS 16
#define HEAD_DIM 64
#define BB 4
#define SS 2048
#define NTOK (BB * SS)  // 8192

typedef __attribute__((ext_vector_type(8))) __bf16 bf16x8;
typedef __attribute__((ext_vector_type(4))) float f32x4;
typedef unsigned short u16;

__device__ __forceinline__ u16 f2bf(float x) {
    union { float f; uint32_t u; } v; v.f = x;
    uint32_t r = v.u + 0x7FFF + ((v.u >> 16) & 1);  // RNE
    return (u16)(r >> 16);
}

// ---------------- fp32 -> bf16 elementwise convert (vectorized) ----------------
__global__ void cvt_f32_bf16(const float* __restrict__ in, u16* __restrict__ out, int n4) {
    int i = blockIdx.x * blockDim.x + threadIdx.x;
    int stride = gridDim.x * blockDim.x;
    for (; i < n4; i += stride) {
        float4 v = ((const float4*)in)[i];
        ushort4 o;
        o.x = f2bf(v.x); o.y = f2bf(v.y); o.z = f2bf(v.z); o.w = f2bf(v.w);
        ((ushort4*)out)[i] = o;
    }
}

// ---------------- transpose fp32 W[K][N] -> bf16 Wt[N][K] ----------------
__global__ void transpose_to_bf16(const float* __restrict__ W, u16* __restrict__ Wt,
                                  int K, int N) {
    __shared__ float tile[32][33];
    int bx = blockIdx.x;  // over N/32
    int by = blockIdx.y;  // over K/32
    int tx = threadIdx.x; // 32
    int ty = threadIdx.y; // 8
    for (int i = 0; i < 4; i++) {
        int kk = ty + i * 8;
        tile[kk][tx] = W[(size_t)(by * 32 + kk) * N + bx * 32 + tx];
    }
    __syncthreads();
    for (int i = 0; i < 4; i++) {
        int nn = ty + i * 8;
        Wt[(size_t)(bx * 32 + nn) * K + by * 32 + tx] = f2bf(tile[tx][nn]);
    }
}

// ---------------- bf16 MFMA GEMM: C[M][N] = A[M][K] @ Bt[N][K]^T + bias ----------------
// MODE 0: C bf16 row-major [M][N]
// MODE 1: C fp32 row-major [M][N]  (final output)
// MODE 2: C bf16 transposed-per-batch: Vt[b][n][t]  (n=dim, t=token-in-batch)
#define BM 64
#define BN 64
#define BK 64
#define LDSS 72  // padded row stride in bf16 elems (144B: 2-way bank alias = free)

template <int MODE>
__global__ __launch_bounds__(256) void gemm_bt(
    const u16* __restrict__ A, const u16* __restrict__ Bt,
    const float* __restrict__ bias, void* __restrict__ C,
    int M, int N, int K) {
    __shared__ u16 Al[BM * LDSS];
    __shared__ u16 Bl[BN * LDSS];
    const int mb = blockIdx.y, nb = blockIdx.x;
    const int tid = threadIdx.x;
    const int w = tid >> 6, lane = tid & 63;
    const int lr = lane & 15, lg = lane >> 4;

    f32x4 acc[4] = {};

    for (int k0 = 0; k0 < K; k0 += BK) {
        // stage A,B tiles: 64 rows x 128B each; 512 16B-chunks per tile
        for (int it = 0; it < 2; it++) {
            int idx = tid + it * 256;
            int r = idx >> 3, c = idx & 7;
            *(float4*)(&Al[r * LDSS + c * 8]) =
                *(const float4*)(A + (size_t)(mb * BM + r) * K + k0 + c * 8);
            *(float4*)(&Bl[r * LDSS + c * 8]) =
                *(const float4*)(Bt + (size_t)(nb * BN + r) * K + k0 + c * 8);
        }
        __syncthreads();
        for (int ks = 0; ks < 2; ks++) {
            bf16x8 af = *(const bf16x8*)(&Al[(w * 16 + lr) * LDSS + ks * 32 + lg * 8]);
            for (int nf = 0; nf < 4; nf++) {
                bf16x8 bfr = *(const bf16x8*)(&Bl[(nf * 16 + lr) * LDSS + ks * 32 + lg * 8]);
                acc[nf] = __builtin_amdgcn_mfma_f32_16x16x32_bf16(af, bfr, acc[nf], 0, 0, 0);
            }
        }
        __syncthreads();
    }

    // epilogue: D[m][n]: n = lane&15 (+16*nf), m = (lane>>4)*4 + reg (+16*w)
    for (int nf = 0; nf < 4; nf++) {
        int n = nb * BN + nf * 16 + lr;
        float bval = bias[n];
        for (int reg = 0; reg < 4; reg++) {
            int m = mb * BM + w * 16 + lg * 4 + reg;
            float val = acc[nf][reg] + bval;
            if (MODE == 0) {
                ((u16*)C)[(size_t)m * N + n] = f2bf(val);
            } else if (MODE == 1) {
                ((float*)C)[(size_t)m * N + n] = val;
            } else {
                int b = m >> 11, t = m & (SS - 1);
                ((u16*)C)[((size_t)b * HEAD_DIM + n) * SS + t] = f2bf(val);
            }
        }
    }
}

// ---------------- flash attention (MQA, non-causal) ----------------
// grid: (S/64, HEADS, B), 256 threads (4 waves), wave w owns q-rows w*16..w*16+15
__global__ __launch_bounds__(256) void attn_kernel(
    const u16* __restrict__ q,   // [NTOK][HIDDEN], col = h*64+d
    const u16* __restrict__ k,   // [NTOK][64]
    const u16* __restrict__ vt,  // [B][64][S]  (dim-major)
    u16* __restrict__ o) {       // [NTOK][HIDDEN]
    const int qt = blockIdx.x, h = blockIdx.y, b = blockIdx.z;
    const int tid = threadIdx.x;
    const int w = tid >> 6, lane = tid & 63;
    const int lr = lane & 15, lg = lane >> 4;

    __shared__ u16 P[4][16 * LDSS];  // per-wave P tile [16 q][64 kv], padded

    const int rowbase = b * SS + qt * 64 + w * 16;

    // Q fragments hoisted to registers (2 k-steps of 32 over HEAD_DIM=64)
    bf16x8 qf[2];
    qf[0] = *(const bf16x8*)(q + (size_t)(rowbase + lr) * HIDDEN + h * 64 + lg * 8);
    qf[1] = *(const bf16x8*)(q + (size_t)(rowbase + lr) * HIDDEN + h * 64 + 32 + lg * 8);

    float m_run[4], l_run[4];
    f32x4 oacc[4] = {};
#pragma unroll
    for (int r = 0; r < 4; r++) { m_run[r] = -1e30f; l_run[r] = 0.f; }

    const float sc = 1.44269504f * 0.125f;  // log2(e) / sqrt(HEAD_DIM)

    for (int kv0 = 0; kv0 < SS; kv0 += 64) {
        // ---- S = Q K^T ----
        f32x4 s[4] = {};
#pragma unroll
        for (int ks = 0; ks < 2; ks++) {
#pragma unroll
            for (int nf = 0; nf < 4; nf++) {
                bf16x8 kf = *(const bf16x8*)(k + (size_t)(b * SS + kv0 + nf * 16 + lr) * HEAD_DIM + ks * 32 + lg * 8);
                s[nf] = __builtin_amdgcn_mfma_f32_16x16x32_bf16(qf[ks], kf, s[nf], 0, 0, 0);
            }
        }
#pragma unroll
        for (int nf = 0; nf < 4; nf++)
#pragma unroll
            for (int r = 0; r < 4; r++) s[nf][r] *= sc;

        // ---- online softmax (row m = lg*4+r, spread across 16 lanes of group lg) ----
        float po[4];
#pragma unroll
        for (int r = 0; r < 4; r++) {
            float mx = fmaxf(fmaxf(s[0][r], s[1][r]), fmaxf(s[2][r], s[3][r]));
            mx = fmaxf(mx, __shfl_xor(mx, 1));
            mx = fmaxf(mx, __shfl_xor(mx, 2));
            mx = fmaxf(mx, __shfl_xor(mx, 4));
            mx = fmaxf(mx, __shfl_xor(mx, 8));
            float mnew = fmaxf(m_run[r], mx);
            po[r] = exp2f(m_run[r] - mnew);
            m_run[r] = mnew;
            float rs = 0.f;
#pragma unroll
            for (int nf = 0; nf < 4; nf++) {
                float p = exp2f(s[nf][r] - mnew);
                s[nf][r] = p;
                rs += p;
            }
            rs += __shfl_xor(rs, 1);
            rs += __shfl_xor(rs, 2);
            rs += __shfl_xor(rs, 4);
            rs += __shfl_xor(rs, 8);
            l_run[r] = l_run[r] * po[r] + rs;
        }

        // ---- P -> LDS (bf16), rescale O ----
#pragma unroll
        for (int nf = 0; nf < 4; nf++)
#pragma unroll
            for (int r = 0; r < 4; r++)
                P[w][(lg * 4 + r) * LDSS + nf * 16 + lr] = f2bf(s[nf][r]);
#pragma unroll
        for (int nf = 0; nf < 4; nf++)
#pragma unroll
            for (int r = 0; r < 4; r++) oacc[nf][r] *= po[r];

        // ---- O += P V ----
#pragma unroll
        for (int ks = 0; ks < 2; ks++) {
            bf16x8 pf = *(const bf16x8*)(&P[w][lr * LDSS + ks * 32 + lg * 8]);
#pragma unroll
            for (int nf = 0; nf < 4; nf++) {
                bf16x8 vf = *(const bf16x8*)(vt + ((size_t)b * HEAD_DIM + nf * 16 + lr) * SS + kv0 + ks * 32 + lg * 8);
                oacc[nf] = __builtin_amdgcn_mfma_f32_16x16x32_bf16(pf, vf, oacc[nf], 0, 0, 0);
            }
        }
    }

    // ---- finalize: O /= l, store bf16 ----
#pragma unroll
    for (int nf = 0; nf < 4; nf++)
#pragma unroll
        for (int r = 0; r < 4; r++) {
            float val = oacc[nf][r] / l_run[r];
            o[(size_t)(rowbase + lg * 4 + r) * HIDDEN + h * 64 + nf * 16 + lr] = f2bf(val);
        }
}

extern "C" void kernel_launch(void* const* d_in, const int* in_sizes, int n_in,
                              void* d_out, int out_size, void* d_ws, size_t ws_size,
                              hipStream_t stream) {
    const float* h  = (const float*)d_in[0];
    const float* Wq = (const float*)d_in[1];
    const float* bq = (const float*)d_in[2];
    const float* Wk = (const float*)d_in[3];
    const float* bk = (const float*)d_in[4];
    const float* Wv = (const float*)d_in[5];
    const float* bv = (const float*)d_in[6];
    const float* Wo = (const float*)d_in[7];
    const float* bo = (const float*)d_in[8];

    // workspace layout (~54 MB total)
    char* ws = (char*)d_ws;
    u16* hbf = (u16*)ws; ws += (size_t)NTOK * HIDDEN * 2;
    u16* Wqt = (u16*)ws; ws += (size_t)HIDDEN * HIDDEN * 2;
    u16* Wkt = (u16*)ws; ws += (size_t)HEAD_DIM * HIDDEN * 2;
    u16* Wvt = (u16*)ws; ws += (size_t)HEAD_DIM * HIDDEN * 2;
    u16* Wot = (u16*)ws; ws += (size_t)HIDDEN * HIDDEN * 2;
    u16* qbf = (u16*)ws; ws += (size_t)NTOK * HIDDEN * 2;
    u16* kbf = (u16*)ws; ws += (size_t)NTOK * HEAD_DIM * 2;
    u16* vtb = (u16*)ws; ws += (size_t)NTOK * HEAD_DIM * 2;
    u16* obf = (u16*)ws; ws += (size_t)NTOK * HIDDEN * 2;

    cvt_f32_bf16<<<2048, 256, 0, stream>>>(h, hbf, NTOK * HIDDEN / 4);
    transpose_to_bf16<<<dim3(HIDDEN / 32, HIDDEN / 32), dim3(32, 8), 0, stream>>>(Wq, Wqt, HIDDEN, HIDDEN);
    transpose_to_bf16<<<dim3(HEAD_DIM / 32, HIDDEN / 32), dim3(32, 8), 0, stream>>>(Wk, Wkt, HIDDEN, HEAD_DIM);
    transpose_to_bf16<<<dim3(HEAD_DIM / 32, HIDDEN / 32), dim3(32, 8), 0, stream>>>(Wv, Wvt, HIDDEN, HEAD_DIM);
    transpose_to_bf16<<<dim3(HIDDEN / 32, HIDDEN / 32), dim3(32, 8), 0, stream>>>(Wo, Wot, HIDDEN, HIDDEN);

    // projections
    gemm_bt<0><<<dim3(HIDDEN / BN, NTOK / BM), 256, 0, stream>>>(hbf, Wqt, bq, qbf, NTOK, HIDDEN, HIDDEN);
    gemm_bt<0><<<dim3(HEAD_DIM / BN, NTOK / BM), 256, 0, stream>>>(hbf, Wkt, bk, kbf, NTOK, HEAD_DIM, HIDDEN);
    gemm_bt<2><<<dim3(HEAD_DIM / BN, NTOK / BM), 256, 0, stream>>>(hbf, Wvt, bv, vtb, NTOK, HEAD_DIM, HIDDEN);

    // attention
    attn_kernel<<<dim3(SS / 64, HEADS, BB), 256, 0, stream>>>(qbf, kbf, vtb, obf);

    // output projection (fp32 out)
    gemm_bt<1><<<dim3(HIDDEN / BN, NTOK / BM), 256, 0, stream>>>(obf, Wot, bo, (float*)d_out, NTOK, HIDDEN, HIDDEN);
}

// Round 2
// 589.737 us; speedup vs baseline: 1.0126x; 1.0126x over previous
//
#include <hip/hip_runtime.h>
#include <hip/hip_bf16.h>
#include <cstdint>

// MQA: B=4, S=2048, HIDDEN=1024, HEADS=16, HEAD_DIM=64
#define HIDDEN 1024
#define HEADS 16
#define HEAD_DIM 64
#define BB 4
#define SS 2048
#define NTOK (BB * SS)  // 8192

typedef __attribute__((ext_vector_type(8))) __bf16 bf16x8;
typedef __attribute__((ext_vector_type(4))) float f32x4;
typedef unsigned short u16;

__device__ __forceinline__ u16 f2bf(float x) {
    union { float f; uint32_t u; } v; v.f = x;
    uint32_t r = v.u + 0x7FFF + ((v.u >> 16) & 1);  // RNE
    return (u16)(r >> 16);
}

// ---------------- fp32 -> bf16 elementwise convert (vectorized) ----------------
__global__ void cvt_f32_bf16(const float* __restrict__ in, u16* __restrict__ out, int n4) {
    int i = blockIdx.x * blockDim.x + threadIdx.x;
    int stride = gridDim.x * blockDim.x;
    for (; i < n4; i += stride) {
        float4 v = ((const float4*)in)[i];
        ushort4 o;
        o.x = f2bf(v.x); o.y = f2bf(v.y); o.z = f2bf(v.z); o.w = f2bf(v.w);
        ((ushort4*)out)[i] = o;
    }
}

// ---------------- transpose fp32 W[K][N] -> bf16 Wt[N][K] ----------------
__global__ void transpose_to_bf16(const float* __restrict__ W, u16* __restrict__ Wt,
                                  int K, int N) {
    __shared__ float tile[32][33];
    int bx = blockIdx.x;  // over N/32
    int by = blockIdx.y;  // over K/32
    int tx = threadIdx.x; // 32
    int ty = threadIdx.y; // 8
    for (int i = 0; i < 4; i++) {
        int kk = ty + i * 8;
        tile[kk][tx] = W[(size_t)(by * 32 + kk) * N + bx * 32 + tx];
    }
    __syncthreads();
    for (int i = 0; i < 4; i++) {
        int nn = ty + i * 8;
        Wt[(size_t)(bx * 32 + nn) * K + by * 32 + tx] = f2bf(tile[tx][nn]);
    }
}

// ---------------- bf16 MFMA GEMM: C[M][N] = A[M][K] @ Bt[N][K]^T + bias ----------------
#define BM 64
#define BN 64
#define BK 64
#define LDSS 72

template <int MODE>
__global__ __launch_bounds__(256) void gemm_bt(
    const u16* __restrict__ A, const u16* __restrict__ Bt,
    const float* __restrict__ bias, void* __restrict__ C,
    int M, int N, int K) {
    __shared__ u16 Al[BM * LDSS];
    __shared__ u16 Bl[BN * LDSS];
    const int mb = blockIdx.y, nb = blockIdx.x;
    const int tid = threadIdx.x;
    const int w = tid >> 6, lane = tid & 63;
    const int lr = lane & 15, lg = lane >> 4;

    f32x4 acc[4] = {};

    for (int k0 = 0; k0 < K; k0 += BK) {
        for (int it = 0; it < 2; it++) {
            int idx = tid + it * 256;
            int r = idx >> 3, c = idx & 7;
            *(float4*)(&Al[r * LDSS + c * 8]) =
                *(const float4*)(A + (size_t)(mb * BM + r) * K + k0 + c * 8);
            *(float4*)(&Bl[r * LDSS + c * 8]) =
                *(const float4*)(Bt + (size_t)(nb * BN + r) * K + k0 + c * 8);
        }
        __syncthreads();
        for (int ks = 0; ks < 2; ks++) {
            bf16x8 af = *(const bf16x8*)(&Al[(w * 16 + lr) * LDSS + ks * 32 + lg * 8]);
            for (int nf = 0; nf < 4; nf++) {
                bf16x8 bfr = *(const bf16x8*)(&Bl[(nf * 16 + lr) * LDSS + ks * 32 + lg * 8]);
                acc[nf] = __builtin_amdgcn_mfma_f32_16x16x32_bf16(af, bfr, acc[nf], 0, 0, 0);
            }
        }
        __syncthreads();
    }

    for (int nf = 0; nf < 4; nf++) {
        int n = nb * BN + nf * 16 + lr;
        float bval = bias[n];
        for (int reg = 0; reg < 4; reg++) {
            int m = mb * BM + w * 16 + lg * 4 + reg;
            float val = acc[nf][reg] + bval;
            if (MODE == 0) {
                ((u16*)C)[(size_t)m * N + n] = f2bf(val);
            } else if (MODE == 1) {
                ((float*)C)[(size_t)m * N + n] = val;
            } else {
                int b = m >> 11, t = m & (SS - 1);
                ((u16*)C)[((size_t)b * HEAD_DIM + n) * SS + t] = f2bf(val);
            }
        }
    }
}

// ---------------- flash attention (MQA, non-causal), swapped QK^T ----------------
// grid: (S/64, HEADS, B), 256 threads (4 waves), wave w owns q-rows w*16..w*16+15
// Swapped trick: st = mfma(K_frag, Q_frag) -> lane holds S^T[kv][q=lane&15]:
// per lane, ALL its 32 scores (KVBLK=128) belong to ONE q-row -> in-register
// row reduce (tree) + 2 shfl_xor (lanes 16/32) instead of 32 shuffles.
#define KVBLK 128
#define PLD 132  // P row stride in bf16 elems; 66 dwords -> 2 mod 32 bank spread

__global__ __launch_bounds__(256) void attn_kernel(
    const u16* __restrict__ q,   // [NTOK][HIDDEN], col = h*64+d
    const u16* __restrict__ k,   // [NTOK][64]
    const u16* __restrict__ vt,  // [B][64][S]  (dim-major)
    u16* __restrict__ o) {       // [NTOK][HIDDEN]
    const int qt = blockIdx.x, h = blockIdx.y, b = blockIdx.z;
    const int tid = threadIdx.x;
    const int w = tid >> 6, lane = tid & 63;
    const int lr = lane & 15, lg = lane >> 4;

    __shared__ u16 P[4][16 * PLD];  // per-wave P tile [16 q][128 kv]

    const int rowbase = b * SS + qt * 64 + w * 16;

    // Q fragments (B-operand: lane holds col q=lr, d-offset lg*8)
    bf16x8 qf[2];
    qf[0] = *(const bf16x8*)(q + (size_t)(rowbase + lr) * HIDDEN + h * 64 + lg * 8);
    qf[1] = *(const bf16x8*)(q + (size_t)(rowbase + lr) * HIDDEN + h * 64 + 32 + lg * 8);

    // per-lane softmax state for q-row lr (replicated across the 4 lg-groups)
    float m_run = -1e30f, l_run = 0.f;
    f32x4 oacc[4] = {};  // PV acc: rows q=lg*4+r, cols d=nf*16+lr

    const float sc = 1.44269504f * 0.125f;  // log2(e)/sqrt(Dh)

    const u16* kbase = k + (size_t)b * SS * HEAD_DIM;
    const u16* vbase = vt + (size_t)b * HEAD_DIM * SS;

    for (int kv0 = 0; kv0 < SS; kv0 += KVBLK) {
        // ---- S^T = K Q^T : st[nf] rows kv = nf*16+lg*4+r, col q=lr ----
        f32x4 st[8] = {};
#pragma unroll
        for (int ks = 0; ks < 2; ks++) {
#pragma unroll
            for (int nf = 0; nf < 8; nf++) {
                bf16x8 kf = *(const bf16x8*)(kbase + (size_t)(kv0 + nf * 16 + lr) * HEAD_DIM + ks * 32 + lg * 8);
                st[nf] = __builtin_amdgcn_mfma_f32_16x16x32_bf16(kf, qf[ks], st[nf], 0, 0, 0);
            }
        }

        // ---- row max: in-register tree over 32 vals + 2 shuffles ----
        float v[32];
#pragma unroll
        for (int nf = 0; nf < 8; nf++)
#pragma unroll
            for (int r = 0; r < 4; r++) v[nf * 4 + r] = st[nf][r];
#pragma unroll
        for (int stw = 16; stw >= 1; stw >>= 1)
#pragma unroll
            for (int i = 0; i < stw; i++) v[i] = fmaxf(v[i], v[i + stw]);
        float mx = v[0];
        mx = fmaxf(mx, __shfl_xor(mx, 16));
        mx = fmaxf(mx, __shfl_xor(mx, 32));

        float mnew = fmaxf(m_run, mx);
        float po = exp2f((m_run - mnew) * sc);
        m_run = mnew;
        float msc = mnew * sc;

        // ---- P = exp2(s*sc - msc); row sum tree ----
        float s2[32];
#pragma unroll
        for (int nf = 0; nf < 8; nf++)
#pragma unroll
            for (int r = 0; r < 4; r++) {
                float p = exp2f(fmaf(st[nf][r], sc, -msc));
                st[nf][r] = p;
                s2[nf * 4 + r] = p;
            }
#pragma unroll
        for (int stw = 16; stw >= 1; stw >>= 1)
#pragma unroll
            for (int i = 0; i < stw; i++) s2[i] += s2[i + stw];
        float rs = s2[0];
        rs += __shfl_xor(rs, 16);
        rs += __shfl_xor(rs, 32);
        l_run = l_run * po + rs;

        // ---- P^T -> LDS as bf16: P_lds[q=lr][kv=nf*16+lg*4 .. +3] ----
#pragma unroll
        for (int nf = 0; nf < 8; nf++) {
            union { uint2 u2; __bf16 bx[4]; } pk;
            pk.bx[0] = (__bf16)st[nf][0];
            pk.bx[1] = (__bf16)st[nf][1];
            pk.bx[2] = (__bf16)st[nf][2];
            pk.bx[3] = (__bf16)st[nf][3];
            *(uint2*)(&P[w][lr * PLD + nf * 16 + lg * 4]) = pk.u2;
        }

        // ---- broadcast po to PV-row layout (q=lg*4+r) and rescale O ----
        float po_q[4];
#pragma unroll
        for (int r = 0; r < 4; r++) po_q[r] = __shfl(po, lg * 4 + r);
#pragma unroll
        for (int nf = 0; nf < 4; nf++)
#pragma unroll
            for (int r = 0; r < 4; r++) oacc[nf][r] *= po_q[r];

        // ---- O += P V ----
#pragma unroll
        for (int ks = 0; ks < 4; ks++) {
            bf16x8 pf = *(const bf16x8*)(&P[w][lr * PLD + ks * 32 + lg * 8]);
#pragma unroll
            for (int nf = 0; nf < 4; nf++) {
                bf16x8 vf = *(const bf16x8*)(vbase + (size_t)(nf * 16 + lr) * SS + kv0 + ks * 32 + lg * 8);
                oacc[nf] = __builtin_amdgcn_mfma_f32_16x16x32_bf16(pf, vf, oacc[nf], 0, 0, 0);
            }
        }
    }

    // ---- finalize: O /= l (broadcast l to PV rows), store bf16 ----
    float li[4];
#pragma unroll
    for (int r = 0; r < 4; r++) li[r] = 1.0f / __shfl(l_run, lg * 4 + r);
#pragma unroll
    for (int nf = 0; nf < 4; nf++)
#pragma unroll
        for (int r = 0; r < 4; r++) {
            float val = oacc[nf][r] * li[r];
            o[(size_t)(rowbase + lg * 4 + r) * HIDDEN + h * 64 + nf * 16 + lr] = f2bf(val);
        }
}

extern "C" void kernel_launch(void* const* d_in, const int* in_sizes, int n_in,
                              void* d_out, int out_size, void* d_ws, size_t ws_size,
                              hipStream_t stream) {
    const float* h  = (const float*)d_in[0];
    const float* Wq = (const float*)d_in[1];
    const float* bq = (const float*)d_in[2];
    const float* Wk = (const float*)d_in[3];
    const float* bk = (const float*)d_in[4];
    const float* Wv = (const float*)d_in[5];
    const float* bv = (const float*)d_in[6];
    const float* Wo = (const float*)d_in[7];
    const float* bo = (const float*)d_in[8];

    char* ws = (char*)d_ws;
    u16* hbf = (u16*)ws; ws += (size_t)NTOK * HIDDEN * 2;
    u16* Wqt = (u16*)ws; ws += (size_t)HIDDEN * HIDDEN * 2;
    u16* Wkt = (u16*)ws; ws += (size_t)HEAD_DIM * HIDDEN * 2;
    u16* Wvt = (u16*)ws; ws += (size_t)HEAD_DIM * HIDDEN * 2;
    u16* Wot = (u16*)ws; ws += (size_t)HIDDEN * HIDDEN * 2;
    u16* qbf = (u16*)ws; ws += (size_t)NTOK * HIDDEN * 2;
    u16* kbf = (u16*)ws; ws += (size_t)NTOK * HEAD_DIM * 2;
    u16* vtb = (u16*)ws; ws += (size_t)NTOK * HEAD_DIM * 2;
    u16* obf = (u16*)ws; ws += (size_t)NTOK * HIDDEN * 2;

    cvt_f32_bf16<<<2048, 256, 0, stream>>>(h, hbf, NTOK * HIDDEN / 4);
    transpose_to_bf16<<<dim3(HIDDEN / 32, HIDDEN / 32), dim3(32, 8), 0, stream>>>(Wq, Wqt, HIDDEN, HIDDEN);
    transpose_to_bf16<<<dim3(HEAD_DIM / 32, HIDDEN / 32), dim3(32, 8), 0, stream>>>(Wk, Wkt, HIDDEN, HEAD_DIM);
    transpose_to_bf16<<<dim3(HEAD_DIM / 32, HIDDEN / 32), dim3(32, 8), 0, stream>>>(Wv, Wvt, HIDDEN, HEAD_DIM);
    transpose_to_bf16<<<dim3(HIDDEN / 32, HIDDEN / 32), dim3(32, 8), 0, stream>>>(Wo, Wot, HIDDEN, HIDDEN);

    gemm_bt<0><<<dim3(HIDDEN / BN, NTOK / BM), 256, 0, stream>>>(hbf, Wqt, bq, qbf, NTOK, HIDDEN, HIDDEN);
    gemm_bt<0><<<dim3(HEAD_DIM / BN, NTOK / BM), 256, 0, stream>>>(hbf, Wkt, bk, kbf, NTOK, HEAD_DIM, HIDDEN);
    gemm_bt<2><<<dim3(HEAD_DIM / BN, NTOK / BM), 256, 0, stream>>>(hbf, Wvt, bv, vtb, NTOK, HEAD_DIM, HIDDEN);

    attn_kernel<<<dim3(SS / 64, HEADS, BB), 256, 0, stream>>>(qbf, kbf, vtb, obf);

    gemm_bt<1><<<dim3(HIDDEN / BN, NTOK / BM), 256, 0, stream>>>(obf, Wot, bo, (float*)d_out, NTOK, HIDDEN, HIDDEN);
}

// Round 3
// 275.934 us; speedup vs baseline: 2.1642x; 2.1372x over previous
//
#include <hip/hip_runtime.h>
#include <hip/hip_bf16.h>
#include <cstdint>

// MQA: B=4, S=2048, HIDDEN=1024, HEADS=16, HEAD_DIM=64
#define HIDDEN 1024
#define HEADS 16
#define HEAD_DIM 64
#define BB 4
#define SS 2048
#define NTOK (BB * SS)  // 8192

typedef __attribute__((ext_vector_type(8))) __bf16 bf16x8;
typedef __attribute__((ext_vector_type(4))) float f32x4;
typedef unsigned short u16;

__device__ __forceinline__ u16 f2bf(float x) {
    union { float f; uint32_t u; } v; v.f = x;
    uint32_t r = v.u + 0x7FFF + ((v.u >> 16) & 1);  // RNE
    return (u16)(r >> 16);
}

typedef __attribute__((address_space(3))) uint32_t lds_u32;
typedef __attribute__((address_space(1))) uint32_t glb_u32;
__device__ __forceinline__ void gload16(const u16* g, u16* l) {
    // dest: wave-uniform base, lane writes base + lane*16
    __builtin_amdgcn_global_load_lds((const glb_u32*)g, (lds_u32*)l, 16, 0, 0);
}

// ---------------- fp32 -> bf16 elementwise convert (vectorized) ----------------
__global__ void cvt_f32_bf16(const float* __restrict__ in, u16* __restrict__ out, int n4) {
    int i = blockIdx.x * blockDim.x + threadIdx.x;
    int stride = gridDim.x * blockDim.x;
    for (; i < n4; i += stride) {
        float4 v = ((const float4*)in)[i];
        ushort4 o;
        o.x = f2bf(v.x); o.y = f2bf(v.y); o.z = f2bf(v.z); o.w = f2bf(v.w);
        ((ushort4*)out)[i] = o;
    }
}

// ---------------- transpose fp32 W[K][N] -> bf16 Wt[N][K] ----------------
__global__ void transpose_to_bf16(const float* __restrict__ W, u16* __restrict__ Wt,
                                  int K, int N) {
    __shared__ float tile[32][33];
    int bx = blockIdx.x;
    int by = blockIdx.y;
    int tx = threadIdx.x;
    int ty = threadIdx.y;
    for (int i = 0; i < 4; i++) {
        int kk = ty + i * 8;
        tile[kk][tx] = W[(size_t)(by * 32 + kk) * N + bx * 32 + tx];
    }
    __syncthreads();
    for (int i = 0; i < 4; i++) {
        int nn = ty + i * 8;
        Wt[(size_t)(bx * 32 + nn) * K + by * 32 + tx] = f2bf(tile[tx][nn]);
    }
}

// ---------------- bf16 MFMA GEMM: C[M][N] = A[M][K] @ Bt[N][K]^T + bias ----------------
#define BM 64
#define BN 64
#define BK 64
#define LDSS 72

template <int MODE>
__global__ __launch_bounds__(256) void gemm_bt(
    const u16* __restrict__ A, const u16* __restrict__ Bt,
    const float* __restrict__ bias, void* __restrict__ C,
    int M, int N, int K) {
    __shared__ u16 Al[BM * LDSS];
    __shared__ u16 Bl[BN * LDSS];
    const int mb = blockIdx.y, nb = blockIdx.x;
    const int tid = threadIdx.x;
    const int w = tid >> 6, lane = tid & 63;
    const int lr = lane & 15, lg = lane >> 4;

    f32x4 acc[4] = {};

    for (int k0 = 0; k0 < K; k0 += BK) {
        for (int it = 0; it < 2; it++) {
            int idx = tid + it * 256;
            int r = idx >> 3, c = idx & 7;
            *(float4*)(&Al[r * LDSS + c * 8]) =
                *(const float4*)(A + (size_t)(mb * BM + r) * K + k0 + c * 8);
            *(float4*)(&Bl[r * LDSS + c * 8]) =
                *(const float4*)(Bt + (size_t)(nb * BN + r) * K + k0 + c * 8);
        }
        __syncthreads();
        for (int ks = 0; ks < 2; ks++) {
            bf16x8 af = *(const bf16x8*)(&Al[(w * 16 + lr) * LDSS + ks * 32 + lg * 8]);
            for (int nf = 0; nf < 4; nf++) {
                bf16x8 bfr = *(const bf16x8*)(&Bl[(nf * 16 + lr) * LDSS + ks * 32 + lg * 8]);
                acc[nf] = __builtin_amdgcn_mfma_f32_16x16x32_bf16(af, bfr, acc[nf], 0, 0, 0);
            }
        }
        __syncthreads();
    }

    for (int nf = 0; nf < 4; nf++) {
        int n = nb * BN + nf * 16 + lr;
        float bval = bias[n];
        for (int reg = 0; reg < 4; reg++) {
            int m = mb * BM + w * 16 + lg * 4 + reg;
            float val = acc[nf][reg] + bval;
            if (MODE == 0) {
                ((u16*)C)[(size_t)m * N + n] = f2bf(val);
            } else if (MODE == 1) {
                ((float*)C)[(size_t)m * N + n] = val;
            } else {
                int b = m >> 11, t = m & (SS - 1);
                ((u16*)C)[((size_t)b * HEAD_DIM + n) * SS + t] = f2bf(val);
            }
        }
    }
}

// ---------------- flash attention v3 (MQA), swapped QK^T + LDS-staged K/V ----------------
// grid: (S/128, HEADS, B), 512 threads (8 waves). Wave w owns q-rows w*16..w*16+15.
// K,V tiles (64 kv x 64 bf16) staged in LDS via global_load_lds, double-buffered,
// XOR-swizzled via pre-swizzled global source (linear LDS dest) + swizzled ds_read.
#define KVB 64
#define NT (SS / KVB)  // 32
#define PLD 72

__global__ __launch_bounds__(512) void attn_kernel(
    const u16* __restrict__ q,   // [NTOK][HIDDEN], col = h*64+d
    const u16* __restrict__ k,   // [NTOK][64]
    const u16* __restrict__ vt,  // [B][64][S]  (dim-major)
    u16* __restrict__ o) {       // [NTOK][HIDDEN]
    const int qt = blockIdx.x, h = blockIdx.y, b = blockIdx.z;
    const int tid = threadIdx.x;
    const int w = tid >> 6, lane = tid & 63;
    const int lr = lane & 15, lg = lane >> 4;

    __shared__ u16 Kl[2][KVB * 64];   // [kv][d], swizzled (c16 ^= kv&7)
    __shared__ u16 Vl[2][KVB * 64];   // [d][kv], swizzled (c16 ^= d&7)
    __shared__ u16 P[8][16 * PLD];    // per-wave P [16 q][64 kv]

    const u16* kbase = k + (size_t)b * SS * HEAD_DIM;
    const u16* vbase = vt + (size_t)b * HEAD_DIM * SS;
    const int rowbase = b * SS + qt * 128 + w * 16;

    // staging source (pre-swizzled): this lane fills LDS 16B-slot (row, c16)
    const int srow = w * 8 + (lane >> 3);      // row within 64-row tile
    const int sc16 = (lane & 7) ^ (srow & 7);  // swizzled 16B-column
    const u16* ksrc = kbase + (size_t)srow * HEAD_DIM + sc16 * 8;
    const u16* vsrc = vbase + (size_t)srow * SS + sc16 * 8;

    // Q fragments (B-operand: lane holds col q=lr, d-offset lg*8)
    bf16x8 qf[2];
    qf[0] = *(const bf16x8*)(q + (size_t)(rowbase + lr) * HIDDEN + h * 64 + lg * 8);
    qf[1] = *(const bf16x8*)(q + (size_t)(rowbase + lr) * HIDDEN + h * 64 + 32 + lg * 8);

    float m_run = -1e30f, l_run = 0.f;
    f32x4 oacc[4] = {};  // rows q=lg*4+r, cols d=nf*16+lr

    const float sc = 1.44269504f * 0.125f;  // log2(e)/sqrt(Dh)

    // prologue: stage tile 0 into buf 0
    gload16(ksrc, &Kl[0][w * 512]);
    gload16(vsrc, &Vl[0][w * 512]);
    asm volatile("s_waitcnt vmcnt(0)" ::: "memory");
    __syncthreads();

    int cur = 0;
    for (int t = 0; t < NT; ++t) {
        // issue next-tile stage (overlaps with compute below)
        if (t + 1 < NT) {
            int kv0n = (t + 1) * KVB;
            gload16(ksrc + (size_t)kv0n * HEAD_DIM, &Kl[cur ^ 1][w * 512]);
            gload16(vsrc + kv0n, &Vl[cur ^ 1][w * 512]);
        }

        // ---- S^T = K Q^T : st[nf] rows kv=nf*16+lg*4+r, col q=lr ----
        f32x4 st[4] = {};
#pragma unroll
        for (int ks = 0; ks < 2; ks++) {
#pragma unroll
            for (int nf = 0; nf < 4; nf++) {
                bf16x8 kf = *(const bf16x8*)(
                    &Kl[cur][(nf * 16 + lr) * 64 + (((ks * 4 + lg) ^ (lr & 7)) * 8)]);
                st[nf] = __builtin_amdgcn_mfma_f32_16x16x32_bf16(kf, qf[ks], st[nf], 0, 0, 0);
            }
        }

        // ---- row max over 16 in-register vals + 2 shuffles ----
        float vv[16];
#pragma unroll
        for (int nf = 0; nf < 4; nf++)
#pragma unroll
            for (int r = 0; r < 4; r++) vv[nf * 4 + r] = st[nf][r];
#pragma unroll
        for (int stw = 8; stw >= 1; stw >>= 1)
#pragma unroll
            for (int i = 0; i < stw; i++) vv[i] = fmaxf(vv[i], vv[i + stw]);
        float mx = vv[0];
        mx = fmaxf(mx, __shfl_xor(mx, 16));
        mx = fmaxf(mx, __shfl_xor(mx, 32));

        float mnew = fmaxf(m_run, mx);
        float po = exp2f((m_run - mnew) * sc);
        m_run = mnew;
        float msc = mnew * sc;

        // ---- P = exp2(s*sc - msc); row sum ----
        float s2[16];
#pragma unroll
        for (int nf = 0; nf < 4; nf++)
#pragma unroll
            for (int r = 0; r < 4; r++) {
                float p = exp2f(fmaf(st[nf][r], sc, -msc));
                st[nf][r] = p;
                s2[nf * 4 + r] = p;
            }
#pragma unroll
        for (int stw = 8; stw >= 1; stw >>= 1)
#pragma unroll
            for (int i = 0; i < stw; i++) s2[i] += s2[i + stw];
        float rs = s2[0];
        rs += __shfl_xor(rs, 16);
        rs += __shfl_xor(rs, 32);
        l_run = l_run * po + rs;

        // ---- P^T -> per-wave LDS as bf16 ----
#pragma unroll
        for (int nf = 0; nf < 4; nf++) {
            union { uint2 u2; __bf16 bx[4]; } pk;
            pk.bx[0] = (__bf16)st[nf][0];
            pk.bx[1] = (__bf16)st[nf][1];
            pk.bx[2] = (__bf16)st[nf][2];
            pk.bx[3] = (__bf16)st[nf][3];
            *(uint2*)(&P[w][lr * PLD + nf * 16 + lg * 4]) = pk.u2;
        }

        // ---- rescale O (broadcast po to PV rows q=lg*4+r) ----
        float po_q[4];
#pragma unroll
        for (int r = 0; r < 4; r++) po_q[r] = __shfl(po, lg * 4 + r);
#pragma unroll
        for (int nf = 0; nf < 4; nf++)
#pragma unroll
            for (int r = 0; r < 4; r++) oacc[nf][r] *= po_q[r];

        // ---- O += P V ----
#pragma unroll
        for (int ks = 0; ks < 2; ks++) {
            bf16x8 pf = *(const bf16x8*)(&P[w][lr * PLD + ks * 32 + lg * 8]);
#pragma unroll
            for (int nf = 0; nf < 4; nf++) {
                bf16x8 vf = *(const bf16x8*)(
                    &Vl[cur][(nf * 16 + lr) * 64 + (((ks * 4 + lg) ^ (lr & 7)) * 8)]);
                oacc[nf] = __builtin_amdgcn_mfma_f32_16x16x32_bf16(pf, vf, oacc[nf], 0, 0, 0);
            }
        }

        // wait for next tile's loads; all waves done reading cur
        asm volatile("s_waitcnt vmcnt(0)" ::: "memory");
        __syncthreads();
        cur ^= 1;
    }

    // ---- finalize ----
    float li[4];
#pragma unroll
    for (int r = 0; r < 4; r++) li[r] = 1.0f / __shfl(l_run, lg * 4 + r);
#pragma unroll
    for (int nf = 0; nf < 4; nf++)
#pragma unroll
        for (int r = 0; r < 4; r++) {
            float val = oacc[nf][r] * li[r];
            o[(size_t)(rowbase + lg * 4 + r) * HIDDEN + h * 64 + nf * 16 + lr] = f2bf(val);
        }
}

extern "C" void kernel_launch(void* const* d_in, const int* in_sizes, int n_in,
                              void* d_out, int out_size, void* d_ws, size_t ws_size,
                              hipStream_t stream) {
    const float* h  = (const float*)d_in[0];
    const float* Wq = (const float*)d_in[1];
    const float* bq = (const float*)d_in[2];
    const float* Wk = (const float*)d_in[3];
    const float* bk = (const float*)d_in[4];
    const float* Wv = (const float*)d_in[5];
    const float* bv = (const float*)d_in[6];
    const float* Wo = (const float*)d_in[7];
    const float* bo = (const float*)d_in[8];

    char* ws = (char*)d_ws;
    u16* hbf = (u16*)ws; ws += (size_t)NTOK * HIDDEN * 2;
    u16* Wqt = (u16*)ws; ws += (size_t)HIDDEN * HIDDEN * 2;
    u16* Wkt = (u16*)ws; ws += (size_t)HEAD_DIM * HIDDEN * 2;
    u16* Wvt = (u16*)ws; ws += (size_t)HEAD_DIM * HIDDEN * 2;
    u16* Wot = (u16*)ws; ws += (size_t)HIDDEN * HIDDEN * 2;
    u16* qbf = (u16*)ws; ws += (size_t)NTOK * HIDDEN * 2;
    u16* kbf = (u16*)ws; ws += (size_t)NTOK * HEAD_DIM * 2;
    u16* vtb = (u16*)ws; ws += (size_t)NTOK * HEAD_DIM * 2;
    u16* obf = (u16*)ws; ws += (size_t)NTOK * HIDDEN * 2;

    cvt_f32_bf16<<<2048, 256, 0, stream>>>(h, hbf, NTOK * HIDDEN / 4);
    transpose_to_bf16<<<dim3(HIDDEN / 32, HIDDEN / 32), dim3(32, 8), 0, stream>>>(Wq, Wqt, HIDDEN, HIDDEN);
    transpose_to_bf16<<<dim3(HEAD_DIM / 32, HIDDEN / 32), dim3(32, 8), 0, stream>>>(Wk, Wkt, HIDDEN, HEAD_DIM);
    transpose_to_bf16<<<dim3(HEAD_DIM / 32, HIDDEN / 32), dim3(32, 8), 0, stream>>>(Wv, Wvt, HIDDEN, HEAD_DIM);
    transpose_to_bf16<<<dim3(HIDDEN / 32, HIDDEN / 32), dim3(32, 8), 0, stream>>>(Wo, Wot, HIDDEN, HIDDEN);

    gemm_bt<0><<<dim3(HIDDEN / BN, NTOK / BM), 256, 0, stream>>>(hbf, Wqt, bq, qbf, NTOK, HIDDEN, HIDDEN);
    gemm_bt<0><<<dim3(HEAD_DIM / BN, NTOK / BM), 256, 0, stream>>>(hbf, Wkt, bk, kbf, NTOK, HEAD_DIM, HIDDEN);
    gemm_bt<2><<<dim3(HEAD_DIM / BN, NTOK / BM), 256, 0, stream>>>(hbf, Wvt, bv, vtb, NTOK, HEAD_DIM, HIDDEN);

    attn_kernel<<<dim3(SS / 128, HEADS, BB), 512, 0, stream>>>(qbf, kbf, vtb, obf);

    gemm_bt<1><<<dim3(HIDDEN / BN, NTOK / BM), 256, 0, stream>>>(obf, Wot, bo, (float*)d_out, NTOK, HIDDEN, HIDDEN);
}

// Round 4
// 251.415 us; speedup vs baseline: 2.3753x; 1.0975x over previous
//
#include <hip/hip_runtime.h>
#include <hip/hip_bf16.h>
#include <cstdint>

// MQA: B=4, S=2048, HIDDEN=1024, HEADS=16, HEAD_DIM=64
#define HIDDEN 1024
#define HEADS 16
#define HEAD_DIM 64
#define BB 4
#define SS 2048
#define NTOK (BB * SS)  // 8192

typedef __attribute__((ext_vector_type(8))) __bf16 bf16x8;
typedef __attribute__((ext_vector_type(4))) float f32x4;
typedef unsigned short u16;

__device__ __forceinline__ u16 f2bf(float x) {
    union { float f; uint32_t u; } v; v.f = x;
    uint32_t r = v.u + 0x7FFF + ((v.u >> 16) & 1);  // RNE
    return (u16)(r >> 16);
}

typedef __attribute__((address_space(3))) uint32_t lds_u32;
typedef __attribute__((address_space(1))) uint32_t glb_u32;
__device__ __forceinline__ void gload16(const u16* g, u16* l) {
    // dest: wave-uniform base, lane writes base + lane*16
    __builtin_amdgcn_global_load_lds((const glb_u32*)g, (lds_u32*)l, 16, 0, 0);
}

// ---------------- fp32 -> bf16 elementwise convert (vectorized) ----------------
__global__ void cvt_f32_bf16(const float* __restrict__ in, u16* __restrict__ out, int n4) {
    int i = blockIdx.x * blockDim.x + threadIdx.x;
    int stride = gridDim.x * blockDim.x;
    for (; i < n4; i += stride) {
        float4 v = ((const float4*)in)[i];
        ushort4 o;
        o.x = f2bf(v.x); o.y = f2bf(v.y); o.z = f2bf(v.z); o.w = f2bf(v.w);
        ((ushort4*)out)[i] = o;
    }
}

// ---------------- transpose fp32 W[K][N] -> bf16 Wt[N][K] ----------------
__global__ void transpose_to_bf16(const float* __restrict__ W, u16* __restrict__ Wt,
                                  int K, int N) {
    __shared__ float tile[32][33];
    int bx = blockIdx.x;
    int by = blockIdx.y;
    int tx = threadIdx.x;
    int ty = threadIdx.y;
    for (int i = 0; i < 4; i++) {
        int kk = ty + i * 8;
        tile[kk][tx] = W[(size_t)(by * 32 + kk) * N + bx * 32 + tx];
    }
    __syncthreads();
    for (int i = 0; i < 4; i++) {
        int nn = ty + i * 8;
        Wt[(size_t)(bx * 32 + nn) * K + by * 32 + tx] = f2bf(tile[tx][nn]);
    }
}

// ---------------- 64^2-tile GEMM (kept for K/V projections, N=64) ----------------
#define BM 64
#define BN 64
#define LDSS 72

template <int MODE>
__global__ __launch_bounds__(256) void gemm_bt(
    const u16* __restrict__ A, const u16* __restrict__ Bt,
    const float* __restrict__ bias, void* __restrict__ C,
    int M, int N, int K) {
    __shared__ u16 Al[BM * LDSS];
    __shared__ u16 Bl[BN * LDSS];
    const int mb = blockIdx.y, nb = blockIdx.x;
    const int tid = threadIdx.x;
    const int w = tid >> 6, lane = tid & 63;
    const int lr = lane & 15, lg = lane >> 4;

    f32x4 acc[4] = {};

    for (int k0 = 0; k0 < K; k0 += 64) {
        for (int it = 0; it < 2; it++) {
            int idx = tid + it * 256;
            int r = idx >> 3, c = idx & 7;
            *(float4*)(&Al[r * LDSS + c * 8]) =
                *(const float4*)(A + (size_t)(mb * BM + r) * K + k0 + c * 8);
            *(float4*)(&Bl[r * LDSS + c * 8]) =
                *(const float4*)(Bt + (size_t)(nb * BN + r) * K + k0 + c * 8);
        }
        __syncthreads();
        for (int ks = 0; ks < 2; ks++) {
            bf16x8 af = *(const bf16x8*)(&Al[(w * 16 + lr) * LDSS + ks * 32 + lg * 8]);
            for (int nf = 0; nf < 4; nf++) {
                bf16x8 bfr = *(const bf16x8*)(&Bl[(nf * 16 + lr) * LDSS + ks * 32 + lg * 8]);
                acc[nf] = __builtin_amdgcn_mfma_f32_16x16x32_bf16(af, bfr, acc[nf], 0, 0, 0);
            }
        }
        __syncthreads();
    }

    for (int nf = 0; nf < 4; nf++) {
        int n = nb * BN + nf * 16 + lr;
        float bval = bias[n];
        for (int reg = 0; reg < 4; reg++) {
            int m = mb * BM + w * 16 + lg * 4 + reg;
            float val = acc[nf][reg] + bval;
            if (MODE == 0) {
                ((u16*)C)[(size_t)m * N + n] = f2bf(val);
            } else {
                int b = m >> 11, t = m & (SS - 1);
                ((u16*)C)[((size_t)b * HEAD_DIM + n) * SS + t] = f2bf(val);
            }
        }
    }
}

// ---------------- m97-pattern 128^2 GEMM for Q-proj / O-proj ----------------
// 256 threads = 4 waves (2x2), each wave 64x64 out (4x4 16x16 frags), BK=64,
// global_load_lds width-16 staging, linear LDS, 2 barriers per K-step.
template <int MODE>  // 0: bf16 out, 1: f32 out
__global__ __launch_bounds__(256) void gemm128(
    const u16* __restrict__ A, const u16* __restrict__ Bt,
    const float* __restrict__ bias, void* __restrict__ C,
    int M, int N, int K) {
    __shared__ u16 Al[128 * 64];
    __shared__ u16 Bl[128 * 64];
    const int mb = blockIdx.y, nb = blockIdx.x;
    const int tid = threadIdx.x;
    const int w = tid >> 6, lane = tid & 63;
    const int lr = lane & 15, lg = lane >> 4;
    const int wr = w >> 1, wc = w & 1;

    f32x4 acc[4][4] = {};

    const int srow = lane >> 3;       // 0..7
    const int scol = (lane & 7) * 8;  // elem col in K-slab
    const u16* Asrc = A + (size_t)(mb * 128 + w * 32 + srow) * K + scol;
    const u16* Bsrc = Bt + (size_t)(nb * 128 + w * 32 + srow) * K + scol;
    u16* Adst = &Al[(w * 32) * 64];
    u16* Bdst = &Bl[(w * 32) * 64];

    for (int k0 = 0; k0 < K; k0 += 64) {
        if (k0) __syncthreads();
#pragma unroll
        for (int i = 0; i < 4; i++) {
            gload16(Asrc + (size_t)(i * 8) * K + k0, Adst + i * 8 * 64);
            gload16(Bsrc + (size_t)(i * 8) * K + k0, Bdst + i * 8 * 64);
        }
        asm volatile("s_waitcnt vmcnt(0)" ::: "memory");
        __syncthreads();

#pragma unroll
        for (int ks = 0; ks < 2; ks++) {
            bf16x8 af[4], bfr[4];
#pragma unroll
            for (int mf = 0; mf < 4; mf++)
                af[mf] = *(const bf16x8*)(&Al[(wr * 64 + mf * 16 + lr) * 64 + ks * 32 + lg * 8]);
#pragma unroll
            for (int nf = 0; nf < 4; nf++)
                bfr[nf] = *(const bf16x8*)(&Bl[(wc * 64 + nf * 16 + lr) * 64 + ks * 32 + lg * 8]);
            __builtin_amdgcn_s_setprio(1);
#pragma unroll
            for (int mf = 0; mf < 4; mf++)
#pragma unroll
                for (int nf = 0; nf < 4; nf++)
                    acc[mf][nf] = __builtin_amdgcn_mfma_f32_16x16x32_bf16(af[mf], bfr[nf], acc[mf][nf], 0, 0, 0);
            __builtin_amdgcn_s_setprio(0);
        }
    }

#pragma unroll
    for (int nf = 0; nf < 4; nf++) {
        int n = nb * 128 + wc * 64 + nf * 16 + lr;
        float bval = bias[n];
#pragma unroll
        for (int mf = 0; mf < 4; mf++)
#pragma unroll
            for (int r = 0; r < 4; r++) {
                int m = mb * 128 + wr * 64 + mf * 16 + lg * 4 + r;
                float val = acc[mf][nf][r] + bval;
                if (MODE == 0) ((u16*)C)[(size_t)m * N + n] = f2bf(val);
                else           ((float*)C)[(size_t)m * N + n] = val;
            }
    }
}

// ---------------- flash attention v4 (MQA), swapped QK^T, 2x-unrolled dbuf ----------------
#define KVB 64
#define NT (SS / KVB)  // 32
#define PLD 72

__device__ __forceinline__ void compute_tile(
    const u16* __restrict__ Klb, const u16* __restrict__ Vlb, u16* __restrict__ Pw,
    const bf16x8 (&qf)[2], f32x4 (&oacc)[4], float& m_run, float& l_run,
    const int lr, const int lg) {
    const float sc = 1.44269504f * 0.125f;  // log2(e)/sqrt(Dh)

    // ---- S^T = K Q^T : st[nf] rows kv=nf*16+lg*4+r, col q=lr ----
    f32x4 st[4] = {};
    __builtin_amdgcn_s_setprio(1);
#pragma unroll
    for (int ks = 0; ks < 2; ks++) {
#pragma unroll
        for (int nf = 0; nf < 4; nf++) {
            bf16x8 kf = *(const bf16x8*)(
                &Klb[(nf * 16 + lr) * 64 + (((ks * 4 + lg) ^ (lr & 7)) * 8)]);
            st[nf] = __builtin_amdgcn_mfma_f32_16x16x32_bf16(kf, qf[ks], st[nf], 0, 0, 0);
        }
    }
    __builtin_amdgcn_s_setprio(0);

    // ---- row max: in-register tree + 2 cross-group shuffles ----
    float vv[16];
#pragma unroll
    for (int nf = 0; nf < 4; nf++)
#pragma unroll
        for (int r = 0; r < 4; r++) vv[nf * 4 + r] = st[nf][r];
#pragma unroll
    for (int stw = 8; stw >= 1; stw >>= 1)
#pragma unroll
        for (int i = 0; i < stw; i++) vv[i] = fmaxf(vv[i], vv[i + stw]);
    float mx = vv[0];
    mx = fmaxf(mx, __shfl_xor(mx, 16));
    mx = fmaxf(mx, __shfl_xor(mx, 32));

    // ---- defer-max (T13): rescale only if max grew past threshold ----
    if (!__all(mx <= m_run + 44.3614f)) {  // 44.36 = 8 / sc
        float mnew = fmaxf(m_run, mx);
        float po = exp2f((m_run - mnew) * sc);
        m_run = mnew;
        l_run *= po;
        float po_q[4];
#pragma unroll
        for (int r = 0; r < 4; r++) po_q[r] = __shfl(po, lg * 4 + r);
#pragma unroll
        for (int nf = 0; nf < 4; nf++)
#pragma unroll
            for (int r = 0; r < 4; r++) oacc[nf][r] *= po_q[r];
    }
    float msc = m_run * sc;

    // ---- P = exp2(s*sc - msc); row sum ----
    float s2[16];
#pragma unroll
    for (int nf = 0; nf < 4; nf++)
#pragma unroll
        for (int r = 0; r < 4; r++) {
            float p = exp2f(fmaf(st[nf][r], sc, -msc));
            st[nf][r] = p;
            s2[nf * 4 + r] = p;
        }
#pragma unroll
    for (int stw = 8; stw >= 1; stw >>= 1)
#pragma unroll
        for (int i = 0; i < stw; i++) s2[i] += s2[i + stw];
    float rs = s2[0];
    rs += __shfl_xor(rs, 16);
    rs += __shfl_xor(rs, 32);
    l_run += rs;

    // ---- P^T -> per-wave LDS as bf16 ----
#pragma unroll
    for (int nf = 0; nf < 4; nf++) {
        union { uint2 u2; __bf16 bx[4]; } pk;
        pk.bx[0] = (__bf16)st[nf][0];
        pk.bx[1] = (__bf16)st[nf][1];
        pk.bx[2] = (__bf16)st[nf][2];
        pk.bx[3] = (__bf16)st[nf][3];
        *(uint2*)(&Pw[lr * PLD + nf * 16 + lg * 4]) = pk.u2;
    }

    // ---- O += P V ----
    __builtin_amdgcn_s_setprio(1);
#pragma unroll
    for (int ks = 0; ks < 2; ks++) {
        bf16x8 pf = *(const bf16x8*)(&Pw[lr * PLD + ks * 32 + lg * 8]);
#pragma unroll
        for (int nf = 0; nf < 4; nf++) {
            bf16x8 vf = *(const bf16x8*)(
                &Vlb[(nf * 16 + lr) * 64 + (((ks * 4 + lg) ^ (lr & 7)) * 8)]);
            oacc[nf] = __builtin_amdgcn_mfma_f32_16x16x32_bf16(pf, vf, oacc[nf], 0, 0, 0);
        }
    }
    __builtin_amdgcn_s_setprio(0);
}

__global__ __launch_bounds__(512) void attn_kernel(
    const u16* __restrict__ q,   // [NTOK][HIDDEN], col = h*64+d
    const u16* __restrict__ k,   // [NTOK][64]
    const u16* __restrict__ vt,  // [B][64][S]  (dim-major)
    u16* __restrict__ o) {       // [NTOK][HIDDEN]
    const int qt = blockIdx.x, h = blockIdx.y, b = blockIdx.z;
    const int tid = threadIdx.x;
    const int w = tid >> 6, lane = tid & 63;
    const int lr = lane & 15, lg = lane >> 4;

    __shared__ u16 Kl[2][KVB * 64];   // [kv][d], swizzled (c16 ^= kv&7)
    __shared__ u16 Vl[2][KVB * 64];   // [d][kv], swizzled (c16 ^= d&7)
    __shared__ u16 P[8][16 * PLD];    // per-wave P [16 q][64 kv]

    const u16* kbase = k + (size_t)b * SS * HEAD_DIM;
    const u16* vbase = vt + (size_t)b * HEAD_DIM * SS;
    const int rowbase = b * SS + qt * 128 + w * 16;

    // staging source (pre-swizzled): lane fills LDS 16B-slot (srow, lane&7)
    const int srow = w * 8 + (lane >> 3);
    const int sc16 = (lane & 7) ^ (srow & 7);
    const u16* ksrc = kbase + (size_t)srow * HEAD_DIM + sc16 * 8;
    const u16* vsrc = vbase + (size_t)srow * SS + sc16 * 8;

    bf16x8 qf[2];
    qf[0] = *(const bf16x8*)(q + (size_t)(rowbase + lr) * HIDDEN + h * 64 + lg * 8);
    qf[1] = *(const bf16x8*)(q + (size_t)(rowbase + lr) * HIDDEN + h * 64 + 32 + lg * 8);

    float m_run = -1e30f, l_run = 0.f;
    f32x4 oacc[4] = {};  // rows q=lg*4+r, cols d=nf*16+lr

#define STAGE(BUF, T)                                                  \
    do {                                                               \
        gload16(ksrc + (size_t)(T) * KVB * HEAD_DIM, &Kl[BUF][w * 512]); \
        gload16(vsrc + (size_t)(T) * KVB, &Vl[BUF][w * 512]);          \
    } while (0)

    // prologue
    STAGE(0, 0);
    asm volatile("s_waitcnt vmcnt(0)" ::: "memory");
    __syncthreads();

    for (int t = 0; t < NT; t += 2) {
        STAGE(1, t + 1);
        compute_tile(&Kl[0][0], &Vl[0][0], &P[w][0], qf, oacc, m_run, l_run, lr, lg);
        asm volatile("s_waitcnt vmcnt(0)" ::: "memory");
        __syncthreads();
        if (t + 2 < NT) STAGE(0, t + 2);
        compute_tile(&Kl[1][0], &Vl[1][0], &P[w][0], qf, oacc, m_run, l_run, lr, lg);
        asm volatile("s_waitcnt vmcnt(0)" ::: "memory");
        __syncthreads();
    }
#undef STAGE

    // ---- finalize ----
    float li[4];
#pragma unroll
    for (int r = 0; r < 4; r++) li[r] = 1.0f / __shfl(l_run, lg * 4 + r);
#pragma unroll
    for (int nf = 0; nf < 4; nf++)
#pragma unroll
        for (int r = 0; r < 4; r++) {
            float val = oacc[nf][r] * li[r];
            o[(size_t)(rowbase + lg * 4 + r) * HIDDEN + h * 64 + nf * 16 + lr] = f2bf(val);
        }
}

extern "C" void kernel_launch(void* const* d_in, const int* in_sizes, int n_in,
                              void* d_out, int out_size, void* d_ws, size_t ws_size,
                              hipStream_t stream) {
    const float* h  = (const float*)d_in[0];
    const float* Wq = (const float*)d_in[1];
    const float* bq = (const float*)d_in[2];
    const float* Wk = (const float*)d_in[3];
    const float* bk = (const float*)d_in[4];
    const float* Wv = (const float*)d_in[5];
    const float* bv = (const float*)d_in[6];
    const float* Wo = (const float*)d_in[7];
    const float* bo = (const float*)d_in[8];

    char* ws = (char*)d_ws;
    u16* hbf = (u16*)ws; ws += (size_t)NTOK * HIDDEN * 2;
    u16* Wqt = (u16*)ws; ws += (size_t)HIDDEN * HIDDEN * 2;
    u16* Wkt = (u16*)ws; ws += (size_t)HEAD_DIM * HIDDEN * 2;
    u16* Wvt = (u16*)ws; ws += (size_t)HEAD_DIM * HIDDEN * 2;
    u16* Wot = (u16*)ws; ws += (size_t)HIDDEN * HIDDEN * 2;
    u16* qbf = (u16*)ws; ws += (size_t)NTOK * HIDDEN * 2;
    u16* kbf = (u16*)ws; ws += (size_t)NTOK * HEAD_DIM * 2;
    u16* vtb = (u16*)ws; ws += (size_t)NTOK * HEAD_DIM * 2;
    u16* obf = (u16*)ws; ws += (size_t)NTOK * HIDDEN * 2;

    cvt_f32_bf16<<<2048, 256, 0, stream>>>(h, hbf, NTOK * HIDDEN / 4);
    transpose_to_bf16<<<dim3(HIDDEN / 32, HIDDEN / 32), dim3(32, 8), 0, stream>>>(Wq, Wqt, HIDDEN, HIDDEN);
    transpose_to_bf16<<<dim3(HEAD_DIM / 32, HIDDEN / 32), dim3(32, 8), 0, stream>>>(Wk, Wkt, HIDDEN, HEAD_DIM);
    transpose_to_bf16<<<dim3(HEAD_DIM / 32, HIDDEN / 32), dim3(32, 8), 0, stream>>>(Wv, Wvt, HIDDEN, HEAD_DIM);
    transpose_to_bf16<<<dim3(HIDDEN / 32, HIDDEN / 32), dim3(32, 8), 0, stream>>>(Wo, Wot, HIDDEN, HIDDEN);

    // projections: Q via 128^2 m97-style; K/V via 64^2 (N=64)
    gemm128<0><<<dim3(HIDDEN / 128, NTOK / 128), 256, 0, stream>>>(hbf, Wqt, bq, qbf, NTOK, HIDDEN, HIDDEN);
    gemm_bt<0><<<dim3(HEAD_DIM / BN, NTOK / BM), 256, 0, stream>>>(hbf, Wkt, bk, kbf, NTOK, HEAD_DIM, HIDDEN);
    gemm_bt<2><<<dim3(HEAD_DIM / BN, NTOK / BM), 256, 0, stream>>>(hbf, Wvt, bv, vtb, NTOK, HEAD_DIM, HIDDEN);

    attn_kernel<<<dim3(SS / 128, HEADS, BB), 512, 0, stream>>>(qbf, kbf, vtb, obf);

    gemm128<1><<<dim3(HIDDEN / 128, NTOK / 128), 256, 0, stream>>>(obf, Wot, bo, (float*)d_out, NTOK, HIDDEN, HIDDEN);
}

// Round 5
// 209.588 us; speedup vs baseline: 2.8493x; 1.1996x over previous
//
#include <hip/hip_runtime.h>
#include <hip/hip_bf16.h>
#include <cstdint>

// MQA: B=4, S=2048, HIDDEN=1024, HEADS=16, HEAD_DIM=64
#define HIDDEN 1024
#define HEADS 16
#define HEAD_DIM 64
#define BB 4
#define SS 2048
#define NTOK (BB * SS)  // 8192

typedef __attribute__((ext_vector_type(8))) __bf16 bf16x8;
typedef __attribute__((ext_vector_type(4))) float f32x4;
typedef unsigned short u16;

__device__ __forceinline__ u16 f2bf(float x) {
    union { float f; uint32_t u; } v; v.f = x;
    uint32_t r = v.u + 0x7FFF + ((v.u >> 16) & 1);  // RNE
    return (u16)(r >> 16);
}
__device__ __forceinline__ float fmax3(float a, float b, float c) {
    return fmaxf(fmaxf(a, b), c);
}

typedef __attribute__((address_space(3))) uint32_t lds_u32;
typedef __attribute__((address_space(1))) uint32_t glb_u32;
__device__ __forceinline__ void gload16(const u16* g, u16* l) {
    __builtin_amdgcn_global_load_lds((const glb_u32*)g, (lds_u32*)l, 16, 0, 0);
}

// ---------------- fp32 -> bf16 elementwise convert ----------------
__global__ void cvt_f32_bf16(const float* __restrict__ in, u16* __restrict__ out, int n4) {
    int i = blockIdx.x * blockDim.x + threadIdx.x;
    int stride = gridDim.x * blockDim.x;
    for (; i < n4; i += stride) {
        float4 v = ((const float4*)in)[i];
        ushort4 o;
        o.x = f2bf(v.x); o.y = f2bf(v.y); o.z = f2bf(v.z); o.w = f2bf(v.w);
        ((ushort4*)out)[i] = o;
    }
}

// ---------------- transpose fp32 W[K][N] -> bf16 Wt[N][K] ----------------
__global__ void transpose_to_bf16(const float* __restrict__ W, u16* __restrict__ Wt,
                                  int K, int N) {
    __shared__ float tile[32][33];
    int bx = blockIdx.x;
    int by = blockIdx.y;
    int tx = threadIdx.x;
    int ty = threadIdx.y;
    for (int i = 0; i < 4; i++) {
        int kk = ty + i * 8;
        tile[kk][tx] = W[(size_t)(by * 32 + kk) * N + bx * 32 + tx];
    }
    __syncthreads();
    for (int i = 0; i < 4; i++) {
        int nn = ty + i * 8;
        Wt[(size_t)(bx * 32 + nn) * K + by * 32 + tx] = f2bf(tile[tx][nn]);
    }
}

// ---------------- m97-pattern 128^2 GEMM (O-projection, f32 out) ----------------
__global__ __launch_bounds__(256) void gemm128_f32(
    const u16* __restrict__ A, const u16* __restrict__ Bt,
    const float* __restrict__ bias, float* __restrict__ C,
    int M, int N, int K) {
    __shared__ u16 Al[128 * 64];
    __shared__ u16 Bl[128 * 64];
    const int mb = blockIdx.y, nb = blockIdx.x;
    const int tid = threadIdx.x;
    const int w = tid >> 6, lane = tid & 63;
    const int lr = lane & 15, lg = lane >> 4;
    const int wr = w >> 1, wc = w & 1;

    f32x4 acc[4][4] = {};

    const int srow = lane >> 3;
    const int scol = (lane & 7) * 8;
    const u16* Asrc = A + (size_t)(mb * 128 + w * 32 + srow) * K + scol;
    const u16* Bsrc = Bt + (size_t)(nb * 128 + w * 32 + srow) * K + scol;
    u16* Adst = &Al[(w * 32) * 64];
    u16* Bdst = &Bl[(w * 32) * 64];

    for (int k0 = 0; k0 < K; k0 += 64) {
        if (k0) __syncthreads();
#pragma unroll
        for (int i = 0; i < 4; i++) {
            gload16(Asrc + (size_t)(i * 8) * K + k0, Adst + i * 8 * 64);
            gload16(Bsrc + (size_t)(i * 8) * K + k0, Bdst + i * 8 * 64);
        }
        asm volatile("s_waitcnt vmcnt(0)" ::: "memory");
        __syncthreads();

#pragma unroll
        for (int ks = 0; ks < 2; ks++) {
            bf16x8 af[4], bfr[4];
#pragma unroll
            for (int mf = 0; mf < 4; mf++)
                af[mf] = *(const bf16x8*)(&Al[(wr * 64 + mf * 16 + lr) * 64 + ks * 32 + lg * 8]);
#pragma unroll
            for (int nf = 0; nf < 4; nf++)
                bfr[nf] = *(const bf16x8*)(&Bl[(wc * 64 + nf * 16 + lr) * 64 + ks * 32 + lg * 8]);
            __builtin_amdgcn_s_setprio(1);
#pragma unroll
            for (int mf = 0; mf < 4; mf++)
#pragma unroll
                for (int nf = 0; nf < 4; nf++)
                    acc[mf][nf] = __builtin_amdgcn_mfma_f32_16x16x32_bf16(af[mf], bfr[nf], acc[mf][nf], 0, 0, 0);
            __builtin_amdgcn_s_setprio(0);
        }
    }

#pragma unroll
    for (int nf = 0; nf < 4; nf++) {
        int n = nb * 128 + wc * 64 + nf * 16 + lr;
        float bval = bias[n];
#pragma unroll
        for (int mf = 0; mf < 4; mf++)
#pragma unroll
            for (int r = 0; r < 4; r++) {
                int m = mb * 128 + wr * 64 + mf * 16 + lg * 4 + r;
                C[(size_t)m * N + n] = acc[mf][nf][r] + bval;
            }
    }
}

// ---------------- fused QKV projection GEMM: N = 1024(Q) + 64(K) + 64(V) ----------------
// Bt_all rows: [0,1024) Wq^T, [1024,1088) Wk^T, [1088,1152) Wv^T. Region uniform per (nb,wc).
#define NPROJ 1152
__global__ __launch_bounds__(256) void gemm_proj(
    const u16* __restrict__ A, const u16* __restrict__ Bt,
    const float* __restrict__ bq, const float* __restrict__ bk, const float* __restrict__ bv,
    u16* __restrict__ qout, u16* __restrict__ kout, u16* __restrict__ vout) {
    __shared__ u16 Al[128 * 64];
    __shared__ u16 Bl[128 * 64];
    const int mb = blockIdx.y, nb = blockIdx.x;
    const int tid = threadIdx.x;
    const int w = tid >> 6, lane = tid & 63;
    const int lr = lane & 15, lg = lane >> 4;
    const int wr = w >> 1, wc = w & 1;

    f32x4 acc[4][4] = {};

    const int srow = lane >> 3;
    const int scol = (lane & 7) * 8;
    const u16* Asrc = A + (size_t)(mb * 128 + w * 32 + srow) * HIDDEN + scol;
    const u16* Bsrc = Bt + (size_t)(nb * 128 + w * 32 + srow) * HIDDEN + scol;
    u16* Adst = &Al[(w * 32) * 64];
    u16* Bdst = &Bl[(w * 32) * 64];

    for (int k0 = 0; k0 < HIDDEN; k0 += 64) {
        if (k0) __syncthreads();
#pragma unroll
        for (int i = 0; i < 4; i++) {
            gload16(Asrc + (size_t)(i * 8) * HIDDEN + k0, Adst + i * 8 * 64);
            gload16(Bsrc + (size_t)(i * 8) * HIDDEN + k0, Bdst + i * 8 * 64);
        }
        asm volatile("s_waitcnt vmcnt(0)" ::: "memory");
        __syncthreads();

#pragma unroll
        for (int ks = 0; ks < 2; ks++) {
            bf16x8 af[4], bfr[4];
#pragma unroll
            for (int mf = 0; mf < 4; mf++)
                af[mf] = *(const bf16x8*)(&Al[(wr * 64 + mf * 16 + lr) * 64 + ks * 32 + lg * 8]);
#pragma unroll
            for (int nf = 0; nf < 4; nf++)
                bfr[nf] = *(const bf16x8*)(&Bl[(wc * 64 + nf * 16 + lr) * 64 + ks * 32 + lg * 8]);
            __builtin_amdgcn_s_setprio(1);
#pragma unroll
            for (int mf = 0; mf < 4; mf++)
#pragma unroll
                for (int nf = 0; nf < 4; nf++)
                    acc[mf][nf] = __builtin_amdgcn_mfma_f32_16x16x32_bf16(af[mf], bfr[nf], acc[mf][nf], 0, 0, 0);
            __builtin_amdgcn_s_setprio(0);
        }
    }

#pragma unroll
    for (int nf = 0; nf < 4; nf++) {
        int n = nb * 128 + wc * 64 + nf * 16 + lr;
        float bval = (n < 1024) ? bq[n] : (n < 1088) ? bk[n - 1024] : bv[n - 1088];
#pragma unroll
        for (int mf = 0; mf < 4; mf++)
#pragma unroll
            for (int r = 0; r < 4; r++) {
                int m = mb * 128 + wr * 64 + mf * 16 + lg * 4 + r;
                float val = acc[mf][nf][r] + bval;
                if (n < 1024) {
                    qout[(size_t)m * 1024 + n] = f2bf(val);
                } else if (n < 1088) {
                    kout[(size_t)m * 64 + (n - 1024)] = f2bf(val);
                } else {
                    int bb = m >> 11, t = m & (SS - 1);
                    vout[((size_t)bb * 64 + (n - 1088)) * SS + t] = f2bf(val);
                }
            }
    }
}

// ---------------- flash attention v5: 32 q-rows/wave, swapped QK^T, dbuf LDS K/V ----------------
#define KVB 64
#define NT (SS / KVB)  // 32
#define PLD 72

__global__ __launch_bounds__(512, 4) void attn_kernel(
    const u16* __restrict__ q,   // [NTOK][HIDDEN], col = h*64+d
    const u16* __restrict__ k,   // [NTOK][64]
    const u16* __restrict__ vt,  // [B][64][S]  (dim-major)
    u16* __restrict__ o) {       // [NTOK][HIDDEN]
    const int qt = blockIdx.x, h = blockIdx.y, b = blockIdx.z;
    const int tid = threadIdx.x;
    const int w = tid >> 6, lane = tid & 63;
    const int lr = lane & 15, lg = lane >> 4;

    __shared__ u16 Kl[2][KVB * 64];      // [kv][d], granule-swizzled
    __shared__ u16 Vl[2][KVB * 64];      // [d][kv], granule-swizzled
    __shared__ u16 P[8][2][16 * PLD];    // per-wave, per-sub P [16 q][64 kv]

    const u16* kbase = k + (size_t)b * SS * HEAD_DIM;
    const u16* vbase = vt + (size_t)b * HEAD_DIM * SS;
    const int rowbase = b * SS + qt * 256 + w * 32;

    // staging source (pre-swizzled): lane fills LDS 16B-slot (srow, lane&7)
    const int srow = w * 8 + (lane >> 3);
    const int sc16 = (lane & 7) ^ (srow & 7);
    const u16* ksrc = kbase + (size_t)srow * HEAD_DIM + sc16 * 8;
    const u16* vsrc = vbase + (size_t)srow * SS + sc16 * 8;

    // Q fragments: sub s covers q-rows rowbase+s*16..+15 (B-operand col = lr)
    bf16x8 qf[2][2];
#pragma unroll
    for (int s = 0; s < 2; s++)
#pragma unroll
        for (int ks = 0; ks < 2; ks++)
            qf[s][ks] = *(const bf16x8*)(q + (size_t)(rowbase + s * 16 + lr) * HIDDEN + h * 64 + ks * 32 + lg * 8);

    // hoisted dynamic LDS offsets (elems); nf/ks/buf deltas are immediates
    const int xr = lr & 7;
    const int kvro0 = lr * 64 + ((lg) ^ xr) * 8;       // ks=0
    const int kvro1 = lr * 64 + ((4 + lg) ^ xr) * 8;   // ks=1
    const int p_wo = lr * PLD + lg * 4;                // + nf*16 (imm)
    const int p_ro = lr * PLD + lg * 8;                // + ks*32 (imm)

    float m_run[2] = {-1e30f, -1e30f}, l_run[2] = {0.f, 0.f};
    f32x4 oacc[2][4] = {};  // [sub][nf], rows q=s*16+lg*4+r, cols d=nf*16+lr

    const float sc = 1.44269504f * 0.125f;  // log2(e)/sqrt(Dh)
    const float THR = 44.3614f;             // 8 / sc

#define STAGE(BUF, T)                                                     \
    do {                                                                  \
        gload16(ksrc + (size_t)(T) * KVB * HEAD_DIM, &Kl[BUF][w * 512]);  \
        gload16(vsrc + (size_t)(T) * KVB, &Vl[BUF][w * 512]);             \
    } while (0)

#define CTILE(BUF)                                                                     \
    do {                                                                               \
        f32x4 st[2][4] = {};                                                           \
        __builtin_amdgcn_s_setprio(1);                                                 \
        _Pragma("unroll") for (int nf = 0; nf < 4; nf++) {                             \
            bf16x8 kf = *(const bf16x8*)(&Kl[BUF][kvro0 + nf * 1024]);                 \
            st[0][nf] = __builtin_amdgcn_mfma_f32_16x16x32_bf16(kf, qf[0][0], st[0][nf], 0, 0, 0); \
            st[1][nf] = __builtin_amdgcn_mfma_f32_16x16x32_bf16(kf, qf[1][0], st[1][nf], 0, 0, 0); \
        }                                                                              \
        _Pragma("unroll") for (int nf = 0; nf < 4; nf++) {                             \
            bf16x8 kf = *(const bf16x8*)(&Kl[BUF][kvro1 + nf * 1024]);                 \
            st[0][nf] = __builtin_amdgcn_mfma_f32_16x16x32_bf16(kf, qf[0][1], st[0][nf], 0, 0, 0); \
            st[1][nf] = __builtin_amdgcn_mfma_f32_16x16x32_bf16(kf, qf[1][1], st[1][nf], 0, 0, 0); \
        }                                                                              \
        __builtin_amdgcn_s_setprio(0);                                                 \
        float mx[2];                                                                   \
        _Pragma("unroll") for (int s = 0; s < 2; s++) {                                \
            float a0 = fmax3(st[s][0][0], st[s][0][1], st[s][0][2]);                   \
            float a1 = fmax3(st[s][0][3], st[s][1][0], st[s][1][1]);                   \
            float a2 = fmax3(st[s][1][2], st[s][1][3], st[s][2][0]);                   \
            float a3 = fmax3(st[s][2][1], st[s][2][2], st[s][2][3]);                   \
            float a4 = fmax3(st[s][3][0], st[s][3][1], st[s][3][2]);                   \
            float b0 = fmax3(a0, a1, a2);                                              \
            float b1 = fmax3(a3, a4, st[s][3][3]);                                     \
            float m2 = fmaxf(b0, b1);                                                  \
            m2 = fmaxf(m2, __shfl_xor(m2, 16));                                        \
            m2 = fmaxf(m2, __shfl_xor(m2, 32));                                        \
            mx[s] = m2;                                                                \
        }                                                                              \
        if (!__all(mx[0] <= m_run[0] + THR && mx[1] <= m_run[1] + THR)) {              \
            _Pragma("unroll") for (int s = 0; s < 2; s++) {                            \
                float mnew = fmaxf(m_run[s], mx[s]);                                   \
                float po = exp2f((m_run[s] - mnew) * sc);                              \
                m_run[s] = mnew;                                                       \
                l_run[s] *= po;                                                        \
                float po_q[4];                                                         \
                _Pragma("unroll") for (int r = 0; r < 4; r++) po_q[r] = __shfl(po, lg * 4 + r); \
                _Pragma("unroll") for (int nf = 0; nf < 4; nf++)                       \
                    _Pragma("unroll") for (int r = 0; r < 4; r++) oacc[s][nf][r] *= po_q[r]; \
            }                                                                          \
        }                                                                              \
        _Pragma("unroll") for (int s = 0; s < 2; s++) {                                \
            float msc = m_run[s] * sc;                                                 \
            float rs = 0.f;                                                            \
            _Pragma("unroll") for (int nf = 0; nf < 4; nf++) {                         \
                union { uint2 u2; __bf16 bx[4]; } pk;                                  \
                _Pragma("unroll") for (int r = 0; r < 4; r++) {                        \
                    float p = exp2f(fmaf(st[s][nf][r], sc, -msc));                     \
                    st[s][nf][r] = p;                                                  \
                    pk.bx[r] = (__bf16)p;                                              \
                }                                                                      \
                *(uint2*)(&P[w][s][p_wo + nf * 16]) = pk.u2;                           \
            }                                                                          \
            float t0 = (st[s][0][0] + st[s][0][1]) + (st[s][0][2] + st[s][0][3]);      \
            float t1 = (st[s][1][0] + st[s][1][1]) + (st[s][1][2] + st[s][1][3]);      \
            float t2 = (st[s][2][0] + st[s][2][1]) + (st[s][2][2] + st[s][2][3]);      \
            float t3 = (st[s][3][0] + st[s][3][1]) + (st[s][3][2] + st[s][3][3]);      \
            rs = (t0 + t1) + (t2 + t3);                                                \
            rs += __shfl_xor(rs, 16);                                                  \
            rs += __shfl_xor(rs, 32);                                                  \
            l_run[s] += rs;                                                            \
        }                                                                              \
        __builtin_amdgcn_s_setprio(1);                                                 \
        {                                                                              \
            bf16x8 pf0 = *(const bf16x8*)(&P[w][0][p_ro]);                             \
            bf16x8 pf1 = *(const bf16x8*)(&P[w][1][p_ro]);                             \
            _Pragma("unroll") for (int nf = 0; nf < 4; nf++) {                         \
                bf16x8 vf = *(const bf16x8*)(&Vl[BUF][kvro0 + nf * 1024]);             \
                oacc[0][nf] = __builtin_amdgcn_mfma_f32_16x16x32_bf16(pf0, vf, oacc[0][nf], 0, 0, 0); \
                oacc[1][nf] = __builtin_amdgcn_mfma_f32_16x16x32_bf16(pf1, vf, oacc[1][nf], 0, 0, 0); \
            }                                                                          \
            pf0 = *(const bf16x8*)(&P[w][0][p_ro + 32]);                               \
            pf1 = *(const bf16x8*)(&P[w][1][p_ro + 32]);                               \
            _Pragma("unroll") for (int nf = 0; nf < 4; nf++) {                         \
                bf16x8 vf = *(const bf16x8*)(&Vl[BUF][kvro1 + nf * 1024]);             \
                oacc[0][nf] = __builtin_amdgcn_mfma_f32_16x16x32_bf16(pf0, vf, oacc[0][nf], 0, 0, 0); \
                oacc[1][nf] = __builtin_amdgcn_mfma_f32_16x16x32_bf16(pf1, vf, oacc[1][nf], 0, 0, 0); \
            }                                                                          \
        }                                                                              \
        __builtin_amdgcn_s_setprio(0);                                                 \
    } while (0)

    // prologue
    STAGE(0, 0);
    asm volatile("s_waitcnt vmcnt(0)" ::: "memory");
    __syncthreads();

    for (int t = 0; t < NT; t += 2) {
        STAGE(1, t + 1);
        CTILE(0);
        asm volatile("s_waitcnt vmcnt(0)" ::: "memory");
        __syncthreads();
        if (t + 2 < NT) STAGE(0, t + 2);
        CTILE(1);
        asm volatile("s_waitcnt vmcnt(0)" ::: "memory");
        __syncthreads();
    }
#undef STAGE
#undef CTILE

    // ---- finalize ----
#pragma unroll
    for (int s = 0; s < 2; s++) {
        float li[4];
#pragma unroll
        for (int r = 0; r < 4; r++) li[r] = 1.0f / __shfl(l_run[s], lg * 4 + r);
#pragma unroll
        for (int nf = 0; nf < 4; nf++)
#pragma unroll
            for (int r = 0; r < 4; r++) {
                float val = oacc[s][nf][r] * li[r];
                o[(size_t)(rowbase + s * 16 + lg * 4 + r) * HIDDEN + h * 64 + nf * 16 + lr] = f2bf(val);
            }
    }
}

extern "C" void kernel_launch(void* const* d_in, const int* in_sizes, int n_in,
                              void* d_out, int out_size, void* d_ws, size_t ws_size,
                              hipStream_t stream) {
    const float* h  = (const float*)d_in[0];
    const float* Wq = (const float*)d_in[1];
    const float* bq = (const float*)d_in[2];
    const float* Wk = (const float*)d_in[3];
    const float* bk = (const float*)d_in[4];
    const float* Wv = (const float*)d_in[5];
    const float* bv = (const float*)d_in[6];
    const float* Wo = (const float*)d_in[7];
    const float* bo = (const float*)d_in[8];

    char* ws = (char*)d_ws;
    u16* hbf  = (u16*)ws; ws += (size_t)NTOK * HIDDEN * 2;
    u16* Wta  = (u16*)ws; ws += (size_t)NPROJ * HIDDEN * 2;   // Wq^T|Wk^T|Wv^T rows
    u16* Wot  = (u16*)ws; ws += (size_t)HIDDEN * HIDDEN * 2;
    u16* qbf  = (u16*)ws; ws += (size_t)NTOK * HIDDEN * 2;
    u16* kbf  = (u16*)ws; ws += (size_t)NTOK * HEAD_DIM * 2;
    u16* vtb  = (u16*)ws; ws += (size_t)NTOK * HEAD_DIM * 2;
    u16* obf  = (u16*)ws; ws += (size_t)NTOK * HIDDEN * 2;

    cvt_f32_bf16<<<2048, 256, 0, stream>>>(h, hbf, NTOK * HIDDEN / 4);
    transpose_to_bf16<<<dim3(HIDDEN / 32, HIDDEN / 32), dim3(32, 8), 0, stream>>>(Wq, Wta, HIDDEN, HIDDEN);
    transpose_to_bf16<<<dim3(HEAD_DIM / 32, HIDDEN / 32), dim3(32, 8), 0, stream>>>(Wk, Wta + (size_t)1024 * HIDDEN, HIDDEN, HEAD_DIM);
    transpose_to_bf16<<<dim3(HEAD_DIM / 32, HIDDEN / 32), dim3(32, 8), 0, stream>>>(Wv, Wta + (size_t)1088 * HIDDEN, HIDDEN, HEAD_DIM);
    transpose_to_bf16<<<dim3(HIDDEN / 32, HIDDEN / 32), dim3(32, 8), 0, stream>>>(Wo, Wot, HIDDEN, HIDDEN);

    // fused QKV projection
    gemm_proj<<<dim3(NPROJ / 128, NTOK / 128), 256, 0, stream>>>(hbf, Wta, bq, bk, bv, qbf, kbf, vtb);

    // attention: 256 q-rows per block, 8 waves x 32 q
    attn_kernel<<<dim3(SS / 256, HEADS, BB), 512, 0, stream>>>(qbf, kbf, vtb, obf);

    // output projection (fp32 out)
    gemm128_f32<<<dim3(HIDDEN / 128, NTOK / 128), 256, 0, stream>>>(obf, Wot, bo, (float*)d_out, NTOK, HIDDEN, HIDDEN);
}